// Round 5
// baseline (728.621 us; speedup 1.0000x reference)
//
#include <hip/hip_runtime.h>
#include <hip/hip_bf16.h>
#include <hip/hip_fp16.h>

// GCN autoencoder, R10:
//   memset -> fused1{gemm1(->h1t slice-major) || bin} -> fill_k(XCD-affine) ->
//   dinv_k -> aggs1(feature-slice x XCD-affine, L2-resident slice) ->
//   gemm2(->h2t slice-major) -> aggs2 -> gemm3
//
// R9 post-mortem: shfl-distribution regressed (83->117us) -- runtime-guarded
// unrolled loads + ds_bpermute/lgkmcnt on the gather critical path serialize
// vmem issue. Reverted to R8's batch-8 + next-batch-prefetch loop shape.
// Structural diagnosis (R7-R9 invariant): FETCH ~203-226MB = 8 XCDs x 25.6MB
// -- every XCD's L2 streams the WHOLE h-table because gathers are random over
// N while blocks span all XCDs. Every edge = LLC round trip (~60% stall).
// R10: feature-slice x XCD affinity. 8 slices of 16 feats; blocks with
// bid&7==s (measured round-robin block->XCD, m09) do slice s for ALL nodes.
// Gather tables stored SLICE-MAJOR (written transposed by the gemms), so each
// XCD's slice is a contiguous 3.2MB (L1) / 1.6MB (L2) L2-RESIDENT region ->
// gathers are L2 hits. Bucket/index reads replicate 8x (~51MB, nontemporal to
// protect the slice); outputs stay row-major (slice-block writes its 32B of
// each row). Same per-feature accumulation order -> bit-identical.
// Falsifier: aggs1 >=80us & FETCH >=180MB -> bid&7->XCD broken -> R11 XCC_ID.

#define TPB 256
#define CAP 64
#define BINCAP 220000   // per-bin edge capacity (E/8=200K expected)
#define FILLW 112       // fill blocks per bin

typedef float v2f __attribute__((ext_vector_type(2)));

// ---------------- helpers ----------------

__device__ __forceinline__ unsigned short f2bf(float f) {
    unsigned u = __float_as_uint(f);
    unsigned r = u + 0x7fffu + ((u >> 16) & 1u);  // RNE
    return (unsigned short)(r >> 16);
}
__device__ __forceinline__ float bf_lo(unsigned u) { return __uint_as_float(u << 16); }
__device__ __forceinline__ float bf_hi(unsigned u) { return __uint_as_float(u & 0xffff0000u); }

// ---------------- GEMM body: out[N,C] = A[N,K] @ W[K,C] (+bias) ----------------
// SLICEU > 0: bf16 output written slice-major [8][N][SLICEU] (uints) for the
// XCD-affine gather; SLICEU == 0: row-major.

template <int K, int C, int TN, bool BIAS, bool INBF, bool OUTBF, int SLICEU>
__device__ __forceinline__ void gemm_body(const void* __restrict__ Ap,
                                          const float* __restrict__ W,
                                          const float* __restrict__ bias,
                                          void* __restrict__ outp, int N, int bid,
                                          float* __restrict__ Ws) {
    constexpr int BM  = 128;
    constexpr int TM  = 8;
    constexpr int BK  = 32;
    constexpr int NCT = C / TN;
    static_assert(NCT * (BM / TM) == TPB, "thread layout");

    int tid = threadIdx.x;
    int tc = tid % NCT;
    int tr = tid / NCT;
    int c0 = tc * TN;
    int r0 = bid * BM + tr * TM;

    float acc[TM][TN] = {};

    for (int k0 = 0; k0 < K; k0 += BK) {
        __syncthreads();
        for (int i = tid * 4; i < BK * C; i += TPB * 4)
            *(float4*)&Ws[i] = *(const float4*)&W[k0 * C + i];
        __syncthreads();

        for (int k = 0; k < BK; k += 4) {
            float4 a[TM];
            uint2  au[TM];
#pragma unroll
            for (int i = 0; i < TM; ++i) {
                int r = r0 + i;
                if (r >= N) r = N - 1;
                if (INBF)
                    au[i] = *(const uint2*)((const unsigned short*)Ap + (size_t)r * K + k0 + k);
                else
                    a[i] = *(const float4*)((const float*)Ap + (size_t)r * K + k0 + k);
            }
#pragma unroll
            for (int kk = 0; kk < 4; ++kk) {
                float w[TN];
#pragma unroll
                for (int j = 0; j < TN; j += 4)
                    *(float4*)&w[j] = *(const float4*)&Ws[(k + kk) * C + c0 + j];
#pragma unroll
                for (int i = 0; i < TM; ++i) {
                    float av;
                    if (INBF) {
                        unsigned uu = (kk < 2) ? au[i].x : au[i].y;
                        av = (kk & 1) ? bf_hi(uu) : bf_lo(uu);
                    } else {
                        av = ((const float*)&a[i])[kk];
                    }
#pragma unroll
                    for (int j = 0; j < TN; ++j) acc[i][j] += av * w[j];
                }
            }
        }
    }

#pragma unroll
    for (int i = 0; i < TM; ++i) {
        int r = r0 + i;
        if (r >= N) continue;
        if (BIAS) {
#pragma unroll
            for (int j = 0; j < TN; ++j) acc[i][j] += bias[c0 + j];
        }
        if (OUTBF) {
            unsigned pk[TN / 2];
#pragma unroll
            for (int j = 0; j < TN; j += 2)
                pk[j / 2] = (unsigned)f2bf(acc[i][j]) | ((unsigned)f2bf(acc[i][j + 1]) << 16);
            if (SLICEU > 0) {
                constexpr int SUU = SLICEU > 0 ? SLICEU : 1;
                int uidx0 = c0 / 2;
                int slice = uidx0 / SUU;
                int su0   = uidx0 % SUU;
                unsigned* ob = (unsigned*)outp + (size_t)slice * N * SUU + (size_t)r * SUU + su0;
                if (TN == 8)      *(uint4*)ob = *(uint4*)pk;
                else if (TN == 4) *(uint2*)ob = *(uint2*)pk;
            } else {
                unsigned short* ob = (unsigned short*)outp + (size_t)r * C + c0;
                if (TN == 8)      *(uint4*)ob = *(uint4*)pk;
                else if (TN == 4) *(uint2*)ob = *(uint2*)pk;
            }
        } else {
            float* of = (float*)outp + (size_t)r * C + c0;
#pragma unroll
            for (int j = 0; j < TN; j += 4)
                *(float4*)&of[j] = *(float4*)&acc[i][j];
        }
    }
}

// standalone GEMM kernel (layers 2, 3)
template <int K, int C, int TN, bool BIAS, bool INBF, bool OUTBF, int SLICEU>
__global__ __launch_bounds__(TPB) void gemm_k(const void* __restrict__ Ap,
                                              const float* __restrict__ W,
                                              const float* __restrict__ bias,
                                              void* __restrict__ outp, int N) {
    __shared__ float Ws[32 * C];
    gemm_body<K, C, TN, BIAS, INBF, OUTBF, SLICEU>(Ap, W, bias, outp, N, blockIdx.x, Ws);
}

// ---------------- fused: gemm1 blocks + edge-binning blocks ----------------

__global__ __launch_bounds__(TPB) void fused1_k(const float* __restrict__ x,
                                                const float* __restrict__ W1,
                                                unsigned* __restrict__ h1t,
                                                const int* __restrict__ src,
                                                const int* __restrict__ dst,
                                                uint2* __restrict__ binBuf,
                                                int* __restrict__ binCnt,
                                                int N, int E, int gb, unsigned M) {
    __shared__ float Ws[32 * 128];
    __shared__ int hist[8], gbase[8], lpos[8];
    if ((int)blockIdx.x < gb) {
        gemm_body<128, 128, 8, false, false, true, 8>(x, W1, nullptr, h1t, N, blockIdx.x, Ws);
    } else {
        int bid = (int)blockIdx.x - gb;
        int tid = (int)threadIdx.x;
        if (tid < 8) { hist[tid] = 0; lpos[tid] = 0; }
        __syncthreads();

        int e0 = (bid * TPB + tid) * 8;
        int ne = E - e0; ne = ne > 8 ? 8 : (ne < 0 ? 0 : ne);
        int ss[8], dd[8], bb8[8];
        if (ne == 8) {
            int4 sa = *(const int4*)&src[e0];
            int4 sb = *(const int4*)&src[e0 + 4];
            int4 da = *(const int4*)&dst[e0];
            int4 db = *(const int4*)&dst[e0 + 4];
            ss[0]=sa.x; ss[1]=sa.y; ss[2]=sa.z; ss[3]=sa.w;
            ss[4]=sb.x; ss[5]=sb.y; ss[6]=sb.z; ss[7]=sb.w;
            dd[0]=da.x; dd[1]=da.y; dd[2]=da.z; dd[3]=da.w;
            dd[4]=db.x; dd[5]=db.y; dd[6]=db.z; dd[7]=db.w;
        } else {
            for (int q = 0; q < ne; ++q) { ss[q] = src[e0 + q]; dd[q] = dst[e0 + q]; }
        }
        for (int q = 0; q < ne; ++q) {
            bb8[q] = (int)(((unsigned long long)(unsigned)dd[q] * M) >> 32);
            atomicAdd(&hist[bb8[q]], 1);
        }
        __syncthreads();
        if (tid < 8) gbase[tid] = atomicAdd(&binCnt[tid], hist[tid]);
        __syncthreads();
        for (int q = 0; q < ne; ++q) {
            int b = bb8[q];
            int p = gbase[b] + atomicAdd(&lpos[b], 1);
            if (p < BINCAP)
                binBuf[(size_t)b * BINCAP + p] = make_uint2((unsigned)ss[q], (unsigned)dd[q]);
        }
    }
}

// ---------------- XCD-affine fill (dst-major bucket) ----------------

__global__ __launch_bounds__(TPB) void fill_k(const uint2* __restrict__ binBuf,
                                              const int* __restrict__ binCnt,
                                              int* __restrict__ cnt,
                                              unsigned* __restrict__ bucket, int N) {
    int bin = (int)blockIdx.x & 7;
    int w   = (int)blockIdx.x >> 3;
    int cb  = binCnt[bin];
    if (cb > BINCAP) cb = BINCAP;
    const uint2* eb = binBuf + (size_t)bin * BINCAP;

    for (int base = w * (TPB * 8); base < cb; base += FILLW * (TPB * 8)) {
        int e0 = base + (int)threadIdx.x * 8;
        if (e0 + 8 <= cb) {
            unsigned s[8], d[8];
#pragma unroll
            for (int q = 0; q < 8; q += 2) {
                uint4 t = *(const uint4*)&eb[e0 + q];
                s[q] = t.x; d[q] = t.y; s[q + 1] = t.z; d[q + 1] = t.w;
            }
            int rr[8];
#pragma unroll
            for (int q = 0; q < 8; ++q) rr[q] = atomicAdd(&cnt[(int)d[q]], 1);
#pragma unroll
            for (int q = 0; q < 8; ++q)
                if (rr[q] < CAP) bucket[(size_t)d[q] * CAP + rr[q]] = s[q];
        } else {
            int lim = e0 + 8 < cb ? e0 + 8 : cb;
            for (int e = e0; e < lim; ++e) {
                uint2 t = eb[e];
                int r = atomicAdd(&cnt[(int)t.y], 1);
                if (r < CAP) bucket[(size_t)t.y * CAP + r] = t.x;
            }
        }
    }
}

// ---------------- dinv precompute: dinv[n] = rsqrt(cnt[n]+1) ----------------

__global__ __launch_bounds__(TPB) void dinv_k(const int* __restrict__ cnt,
                                              float* __restrict__ dinv, int N) {
    int i = blockIdx.x * TPB + (int)threadIdx.x;
    if (i < N) dinv[i] = rsqrtf((float)cnt[i] + 1.0f);
}

// ---------------- XCD-affine sliced aggregation ----------------
// slice = blockIdx.x & 7 (round-robin block->XCD). ht is slice-major
// [8][N][SU] uints; XCD s only touches its contiguous N*SU*4-byte slice
// (3.2MB L1 / 1.6MB L2) -> L2-resident -> gathers are L2 hits.
// Loop shape = R8's proven batch-8 + next-batch bucket prefetch (no shfl,
// no runtime-guarded unrolls). Bucket reads nontemporal to protect the slice.
// Output row-major (this block writes its slice's 4*SU bytes of each row).

template <int SU, bool RELU, bool OUTBF>
__global__ __launch_bounds__(TPB) void aggs_k(const unsigned* __restrict__ ht,
                                              const float* __restrict__ dinv,
                                              const int* __restrict__ cnt,
                                              const unsigned* __restrict__ bucket,
                                              const float* __restrict__ bias,
                                              void* __restrict__ outp, int N) {
    constexpr int NPB = TPB / SU;        // nodes per block: 32 (SU=8) / 64 (SU=4)
    int slice = (int)blockIdx.x & 7;
    int chunk = (int)blockIdx.x >> 3;
    int ln = (int)threadIdx.x / SU;
    int fl = (int)threadIdx.x % SU;
    int n  = chunk * NPB + ln;
    if (n >= N) return;

    const unsigned* hs = ht + (size_t)slice * N * SU;  // this XCD's L2-resident slice

    int cfull = cnt[n];
    float di = dinv[n];
    unsigned us = hs[(size_t)n * SU + fl];
    float ax = bf_lo(us) * (di * di);
    float ay = bf_hi(us) * (di * di);

    int cn = cfull < CAP ? cfull : CAP;
    const unsigned* brow = bucket + (size_t)n * CAP;

    int nfull = cn & ~7;
    int s[8], sn2[8];
    if (nfull > 0) {
#pragma unroll
        for (int q = 0; q < 8; ++q) s[q] = (int)__builtin_nontemporal_load(&brow[q]);
    }
    for (int j = 0; j < nfull; ) {
        int jn = j + 8;
        bool more = jn < nfull;
        if (more) {
#pragma unroll
            for (int q = 0; q < 8; ++q) sn2[q] = (int)__builtin_nontemporal_load(&brow[jn + q]);
        }
        unsigned v[8];
        float ds[8];
#pragma unroll
        for (int q = 0; q < 8; ++q) {
            v[q]  = hs[(size_t)s[q] * SU + fl];
            ds[q] = dinv[s[q]];
        }
#pragma unroll
        for (int q = 0; q < 8; ++q) {
            float c = ds[q] * di;
            ax += c * bf_lo(v[q]);
            ay += c * bf_hi(v[q]);
        }
        if (more) {
#pragma unroll
            for (int q = 0; q < 8; ++q) s[q] = sn2[q];
        }
        j = jn;
    }
    for (int j = nfull; j < cn; ++j) {
        int sx = (int)brow[j];
        unsigned v = hs[(size_t)sx * SU + fl];
        float c = dinv[sx] * di;
        ax += c * bf_lo(v);
        ay += c * bf_hi(v);
    }

    int uidx = slice * SU + fl;            // uint index within the full row
    float rx = ax + bias[2 * uidx];
    float ry = ay + bias[2 * uidx + 1];
    if (RELU) { rx = fmaxf(rx, 0.f); ry = fmaxf(ry, 0.f); }
    if (OUTBF) {
        unsigned pk = (unsigned)f2bf(rx) | ((unsigned)f2bf(ry) << 16);
        ((unsigned*)outp)[(size_t)n * (8 * SU) + uidx] = pk;
    } else {
        v2f r; r.x = rx; r.y = ry;
        __builtin_nontemporal_store(r, (v2f*)outp + (size_t)n * (8 * SU) + uidx);
    }
}

// ---------------- launch ----------------

extern "C" void kernel_launch(void* const* d_in, const int* in_sizes, int n_in,
                              void* d_out, int out_size, void* d_ws, size_t ws_size,
                              hipStream_t stream) {
    const float* x    = (const float*)d_in[0];
    const int*   eidx = (const int*)d_in[1];
    const float* W1   = (const float*)d_in[2];
    const float* b1   = (const float*)d_in[3];
    const float* W2   = (const float*)d_in[4];
    const float* b2   = (const float*)d_in[5];
    const float* Wd   = (const float*)d_in[6];
    const float* bd   = (const float*)d_in[7];

    const int N = in_sizes[0] / 128;   // 100000
    const int E = in_sizes[1] / 2;     // 1600000
    const int* src = eidx;
    const int* dst = eidx + E;

    size_t off = 0;
    auto alloc = [&](size_t bytes) {
        void* p = (char*)d_ws + off;
        off += (bytes + 255) & ~(size_t)255;
        return p;
    };
    int*      cnt     = (int*)alloc((size_t)N * 4);
    float*    dinv    = (float*)alloc((size_t)N * 4);
    unsigned* bucket  = (unsigned*)alloc((size_t)N * CAP * 4);  // 25.6 MB, dst-major [N][CAP]
    unsigned* h1t     = (unsigned*)alloc((size_t)N * 64 * 4);   // bf16 slice-major [8][N][8]
    unsigned* h2t     = (unsigned*)alloc((size_t)N * 32 * 4);   // bf16 slice-major [8][N][4]
    unsigned* hrelu_b = (unsigned*)alloc((size_t)N * 64 * 4);   // bf16 row-major [N,128]
    int*      binCnt  = (int*)alloc(256);
    // binBuf (8*BINCAP*8B = 14.1MB) overlays hrelu_b: dead before agg1 writes it.
    uint2*    binBuf  = (uint2*)hrelu_b;
    (void)ws_size;

    float* x_recon = (float*)d_out;                    // [N,128]
    float* z_out   = (float*)d_out + (size_t)N * 128;  // [N,64]

    const int gb = (N + 127) / 128;                 // 782 gemm blocks
    const int bb = (E + TPB * 8 - 1) / (TPB * 8);   // 782 bin blocks
    const unsigned M = (unsigned)((8ULL << 32) / (unsigned)N);  // bin multiplier

    (void)hipMemsetAsync(cnt, 0, (size_t)N * 4, stream);
    (void)hipMemsetAsync(binCnt, 0, 256, stream);

    // fused: gemm1 (slice-major out) || edge binning
    fused1_k<<<gb + bb, TPB, 0, stream>>>(x, W1, h1t, src, dst, binBuf, binCnt, N, E, gb, M);
    // XCD-affine count+fill
    fill_k<<<8 * FILLW, TPB, 0, stream>>>(binBuf, binCnt, cnt, bucket, N);
    // dinv table
    dinv_k<<<(N + TPB - 1) / TPB, TPB, 0, stream>>>(cnt, dinv, N);

    // layer 1 aggregation: 8 slices x 3125 chunks (32 nodes/chunk)
    aggs_k<8, true, true><<<8 * ((N + 31) / 32), TPB, 0, stream>>>(
        h1t, dinv, cnt, bucket, b1, hrelu_b, N);
    // layer 2 gemm (slice-major out)
    gemm_k<128, 64, 4, false, true, true, 4><<<gb, TPB, 0, stream>>>(hrelu_b, W2, nullptr, h2t, N);
    // layer 2 aggregation: 8 slices x 1563 chunks (64 nodes/chunk)
    aggs_k<4, false, false><<<8 * ((N + 63) / 64), TPB, 0, stream>>>(
        h2t, dinv, cnt, bucket, b2, z_out, N);
    // decode
    gemm_k<64, 128, 8, true, false, false, 0><<<gb, TPB, 0, stream>>>(z_out, Wd, bd, x_recon, N);
}

// Round 6
// 497.252 us; speedup vs baseline: 1.4653x; 1.4653x over previous
//
#include <hip/hip_runtime.h>
#include <hip/hip_bf16.h>
#include <hip/hip_fp16.h>

// GCN autoencoder, R11:
//   memset(cnt) -> fused1{filter-fill(XCD-affine, scans all edges) || gemm1} ->
//   dinv_k -> agg1(R8-exact) -> gemm2 -> agg2+decode(fused gemm3) 
//
// R10 post-mortem: slice-affinity regressed 2.6x. FETCH unchanged 227MB: the
// bucket/edge streams (~200MB replicated) flow through the same 4MB L2 and
// evict the "resident" 3.2MB slice; plus 8x vmem op count. Structural lesson:
// the 8x25.6MB h-table replication across non-coherent L2s is inherent to a
// random gather; R8's 83us \approx LLC-fill rate ~3TB/s. Stop attacking it.
// R11: restore R8 agg EXACTLY (rank-major bucket, batch-8+prefetch, dinv) and
// delete passes instead:
//  (a) filter-fill fused into fused1: fill blocks (bid&7=XCD bin) scan ALL
//      edges (L3-hot, ~30us) and keep their bin's -> binning pass, binBuf
//      (12.8MB w + 12.8MB r), and fill_k dispatch all deleted.
//  (b) decode fused into agg2: block's 8 z-rows -> 2KB LDS -> x64 dot with
//      L2-hot Wd -> x_recon. gemm3 dispatch + z round-trip deleted.
// Numerics: rank order + fp32 reorder only -> absmax ~0.00098 unchanged.

#define TPB 256
#define CAP 64
#define FILLW 112       // fill blocks per bin (8*FILLW = 896 fill blocks)

typedef float v2f __attribute__((ext_vector_type(2)));

// ---------------- helpers ----------------

__device__ __forceinline__ unsigned short f2bf(float f) {
    unsigned u = __float_as_uint(f);
    unsigned r = u + 0x7fffu + ((u >> 16) & 1u);  // RNE
    return (unsigned short)(r >> 16);
}
__device__ __forceinline__ float bf_lo(unsigned u) { return __uint_as_float(u << 16); }
__device__ __forceinline__ float bf_hi(unsigned u) { return __uint_as_float(u & 0xffff0000u); }

// ---------------- GEMM body: out[N,C] = A[N,K] @ W[K,C] (+bias) ----------------
// (R8 form: row-major outputs)

template <int K, int C, int TN, bool BIAS, bool INBF, bool OUTBF>
__device__ __forceinline__ void gemm_body(const void* __restrict__ Ap,
                                          const float* __restrict__ W,
                                          const float* __restrict__ bias,
                                          void* __restrict__ outp, int N, int bid,
                                          float* __restrict__ Ws) {
    constexpr int BM  = 128;
    constexpr int TM  = 8;
    constexpr int BK  = 32;
    constexpr int NCT = C / TN;
    static_assert(NCT * (BM / TM) == TPB, "thread layout");

    int tid = threadIdx.x;
    int tc = tid % NCT;
    int tr = tid / NCT;
    int c0 = tc * TN;
    int r0 = bid * BM + tr * TM;

    float acc[TM][TN] = {};

    for (int k0 = 0; k0 < K; k0 += BK) {
        __syncthreads();
        for (int i = tid * 4; i < BK * C; i += TPB * 4)
            *(float4*)&Ws[i] = *(const float4*)&W[k0 * C + i];
        __syncthreads();

        for (int k = 0; k < BK; k += 4) {
            float4 a[TM];
            uint2  au[TM];
#pragma unroll
            for (int i = 0; i < TM; ++i) {
                int r = r0 + i;
                if (r >= N) r = N - 1;
                if (INBF)
                    au[i] = *(const uint2*)((const unsigned short*)Ap + (size_t)r * K + k0 + k);
                else
                    a[i] = *(const float4*)((const float*)Ap + (size_t)r * K + k0 + k);
            }
#pragma unroll
            for (int kk = 0; kk < 4; ++kk) {
                float w[TN];
#pragma unroll
                for (int j = 0; j < TN; j += 4)
                    *(float4*)&w[j] = *(const float4*)&Ws[(k + kk) * C + c0 + j];
#pragma unroll
                for (int i = 0; i < TM; ++i) {
                    float av;
                    if (INBF) {
                        unsigned uu = (kk < 2) ? au[i].x : au[i].y;
                        av = (kk & 1) ? bf_hi(uu) : bf_lo(uu);
                    } else {
                        av = ((const float*)&a[i])[kk];
                    }
#pragma unroll
                    for (int j = 0; j < TN; ++j) acc[i][j] += av * w[j];
                }
            }
        }
    }

#pragma unroll
    for (int i = 0; i < TM; ++i) {
        int r = r0 + i;
        if (r >= N) continue;
        if (BIAS) {
#pragma unroll
            for (int j = 0; j < TN; ++j) acc[i][j] += bias[c0 + j];
        }
        if (OUTBF) {
            unsigned short* ob = (unsigned short*)outp + (size_t)r * C + c0;
            unsigned pk[TN / 2];
#pragma unroll
            for (int j = 0; j < TN; j += 2)
                pk[j / 2] = (unsigned)f2bf(acc[i][j]) | ((unsigned)f2bf(acc[i][j + 1]) << 16);
            if (TN == 8)      *(uint4*)ob = *(uint4*)pk;
            else if (TN == 4) *(uint2*)ob = *(uint2*)pk;
        } else {
            float* of = (float*)outp + (size_t)r * C + c0;
#pragma unroll
            for (int j = 0; j < TN; j += 4)
                *(float4*)&of[j] = *(float4*)&acc[i][j];
        }
    }
}

// standalone GEMM kernel (layer 2)
template <int K, int C, int TN, bool BIAS, bool INBF, bool OUTBF>
__global__ __launch_bounds__(TPB) void gemm_k(const void* __restrict__ Ap,
                                              const float* __restrict__ W,
                                              const float* __restrict__ bias,
                                              void* __restrict__ outp, int N) {
    __shared__ float Ws[32 * C];
    gemm_body<K, C, TN, BIAS, INBF, OUTBF>(Ap, W, bias, outp, N, blockIdx.x, Ws);
}

// ---------------- fused: filter-fill blocks + gemm1 blocks ----------------
// fill arm (bid < 8*FILLW): bin = bid&7 == XCD id (round-robin dispatch).
// Each block scans a contiguous edge range (L3-hot after first touch) and
// processes only edges whose dst falls in its bin -> cnt atomics execute in
// the owning XCD's L2, bucket[r*N+d] writes merge there. No binning pass.
// bin(d) = (d * M) >> 32 with M = floor(2^35 / N).

__global__ __launch_bounds__(TPB) void fused1_k(const float* __restrict__ x,
                                                const float* __restrict__ W1,
                                                unsigned* __restrict__ h1b,
                                                const int* __restrict__ src,
                                                const int* __restrict__ dst,
                                                int* __restrict__ cnt,
                                                unsigned* __restrict__ bucket,
                                                int N, int E, int span, unsigned M) {
    __shared__ float Ws[32 * 128];
    constexpr int FB = 8 * FILLW;
    int bid = (int)blockIdx.x;
    if (bid >= FB) {
        gemm_body<128, 128, 8, false, false, true>(x, W1, nullptr, h1b, N, bid - FB, Ws);
    } else {
        int bin = bid & 7;
        int w   = bid >> 3;
        int lo  = w * span;
        int hi  = lo + span; if (hi > E) hi = E;
        for (int e0 = lo + (int)threadIdx.x * 4; e0 < hi; e0 += TPB * 4) {
            int4 d4 = *(const int4*)&dst[e0];
            int4 s4 = *(const int4*)&src[e0];
            int dd[4] = {d4.x, d4.y, d4.z, d4.w};
            int ss[4] = {s4.x, s4.y, s4.z, s4.w};
#pragma unroll
            for (int q = 0; q < 4; ++q) {
                int b = (int)(((unsigned long long)(unsigned)dd[q] * M) >> 32);
                if (b == bin) {
                    int r = atomicAdd(&cnt[dd[q]], 1);
                    if (r < CAP) bucket[(size_t)r * N + dd[q]] = (unsigned)ss[q];
                }
            }
        }
    }
}

// ---------------- dinv precompute: dinv[n] = rsqrt(cnt[n]+1) ----------------

__global__ __launch_bounds__(TPB) void dinv_k(const int* __restrict__ cnt,
                                              float* __restrict__ dinv, int N) {
    int i = blockIdx.x * TPB + (int)threadIdx.x;
    if (i < N) dinv[i] = rsqrtf((float)cnt[i] + 1.0f);
}

// ---------------- bucket gather aggregation (R8-exact) ----------------
// rank-major bucket [CAP][N]; dinv-table coef; batch-8 + next-batch prefetch.

template <int F2, bool RELU, bool OUTBF>
__global__ __launch_bounds__(TPB) void agg_k(const unsigned* __restrict__ h,
                                             const float* __restrict__ dinv,
                                             const int* __restrict__ cnt,
                                             const unsigned* __restrict__ bucket,
                                             const float* __restrict__ bias,
                                             void* __restrict__ outp, int N) {
    constexpr int NPB = TPB / F2;
    int ln = threadIdx.x / F2;
    int f2 = threadIdx.x % F2;
    int n  = blockIdx.x * NPB + ln;
    if (n >= N) return;

    int cfull = cnt[n];
    float di = dinv[n];
    const unsigned* hp = h + f2;
    unsigned us = hp[(size_t)n * F2];
    v2f acc;
    acc.x = bf_lo(us) * (di * di);
    acc.y = bf_hi(us) * (di * di);

    int cn = cfull < CAP ? cfull : CAP;
    const unsigned* bp = bucket + n;  // rank-major: plane stride = N

    int nfull = cn & ~7;
    int s[8], sn2[8];
    if (nfull > 0) {
#pragma unroll
        for (int q = 0; q < 8; ++q) s[q] = (int)bp[(size_t)q * N];
    }
    for (int j = 0; j < nfull; ) {
        int jn = j + 8;
        bool more = jn < nfull;
        if (more) {
#pragma unroll
            for (int q = 0; q < 8; ++q) sn2[q] = (int)bp[(size_t)(jn + q) * N];
        }
        unsigned v[8];
        float ds[8];
#pragma unroll
        for (int q = 0; q < 8; ++q) {
            v[q]  = hp[(size_t)s[q] * F2];
            ds[q] = dinv[s[q]];
        }
#pragma unroll
        for (int q = 0; q < 8; ++q) {
            float c = ds[q] * di;
            v2f hv; hv.x = bf_lo(v[q]); hv.y = bf_hi(v[q]);
            acc += hv * c;
        }
        if (more) {
#pragma unroll
            for (int q = 0; q < 8; ++q) s[q] = sn2[q];
        }
        j = jn;
    }
    for (int j = nfull; j < cn; ++j) {
        int sx = (int)bp[(size_t)j * N];
        unsigned v = hp[(size_t)sx * F2];
        float c = dinv[sx] * di;
        acc.x += c * bf_lo(v);
        acc.y += c * bf_hi(v);
    }

    float rx = acc.x + bias[2 * f2];
    float ry = acc.y + bias[2 * f2 + 1];
    if (RELU) { rx = fmaxf(rx, 0.f); ry = fmaxf(ry, 0.f); }
    if (OUTBF) {
        unsigned pk = (unsigned)f2bf(rx) | ((unsigned)f2bf(ry) << 16);
        ((unsigned*)outp)[(size_t)n * F2 + f2] = pk;
    } else {
        v2f r; r.x = rx; r.y = ry;
        __builtin_nontemporal_store(r, (v2f*)outp + (size_t)n * F2 + f2);
    }
}

// ---------------- agg2 + fused decode ----------------
// agg body identical to agg_k<32,false,*>; z rows stashed in LDS; decode
// epilogue computes x_recon[8 nodes][128] from LDS z + L2-hot Wd (32KB).

__global__ __launch_bounds__(TPB) void agg2g_k(const unsigned* __restrict__ h,
                                               const float* __restrict__ dinv,
                                               const int* __restrict__ cnt,
                                               const unsigned* __restrict__ bucket,
                                               const float* __restrict__ bias,
                                               const float* __restrict__ Wd,
                                               const float* __restrict__ bd,
                                               float* __restrict__ z_out,
                                               float* __restrict__ x_recon, int N) {
    constexpr int F2 = 32, NPB = TPB / F2;  // 8 nodes/block
    __shared__ float zl[NPB][64];
    int ln = (int)threadIdx.x / F2;
    int f2 = (int)threadIdx.x % F2;
    int n  = blockIdx.x * NPB + ln;

    if (n < N) {
        int cfull = cnt[n];
        float di = dinv[n];
        const unsigned* hp = h + f2;
        unsigned us = hp[(size_t)n * F2];
        v2f acc;
        acc.x = bf_lo(us) * (di * di);
        acc.y = bf_hi(us) * (di * di);

        int cn = cfull < CAP ? cfull : CAP;
        const unsigned* bp = bucket + n;

        int nfull = cn & ~7;
        int s[8], sn2[8];
        if (nfull > 0) {
#pragma unroll
            for (int q = 0; q < 8; ++q) s[q] = (int)bp[(size_t)q * N];
        }
        for (int j = 0; j < nfull; ) {
            int jn = j + 8;
            bool more = jn < nfull;
            if (more) {
#pragma unroll
                for (int q = 0; q < 8; ++q) sn2[q] = (int)bp[(size_t)(jn + q) * N];
            }
            unsigned v[8];
            float ds[8];
#pragma unroll
            for (int q = 0; q < 8; ++q) {
                v[q]  = hp[(size_t)s[q] * F2];
                ds[q] = dinv[s[q]];
            }
#pragma unroll
            for (int q = 0; q < 8; ++q) {
                float c = ds[q] * di;
                v2f hv; hv.x = bf_lo(v[q]); hv.y = bf_hi(v[q]);
                acc += hv * c;
            }
            if (more) {
#pragma unroll
                for (int q = 0; q < 8; ++q) s[q] = sn2[q];
            }
            j = jn;
        }
        for (int j = nfull; j < cn; ++j) {
            int sx = (int)bp[(size_t)j * N];
            unsigned v = hp[(size_t)sx * F2];
            float c = dinv[sx] * di;
            acc.x += c * bf_lo(v);
            acc.y += c * bf_hi(v);
        }

        float rx = acc.x + bias[2 * f2];
        float ry = acc.y + bias[2 * f2 + 1];
        v2f r; r.x = rx; r.y = ry;
        __builtin_nontemporal_store(r, (v2f*)z_out + (size_t)n * F2 + f2);
        *(v2f*)&zl[ln][2 * f2] = r;
    }
    __syncthreads();

    // decode: thread t -> node t/32, cols (t%32)*4 .. +3
    int dn = (int)threadIdx.x / 32;
    int c0 = ((int)threadIdx.x % 32) * 4;
    int nn = blockIdx.x * NPB + dn;
    if (nn < N) {
        float a0 = bd[c0], a1 = bd[c0 + 1], a2 = bd[c0 + 2], a3 = bd[c0 + 3];
#pragma unroll 4
        for (int k = 0; k < 64; ++k) {
            float zv = zl[dn][k];
            float4 w = *(const float4*)&Wd[k * 128 + c0];
            a0 += zv * w.x; a1 += zv * w.y; a2 += zv * w.z; a3 += zv * w.w;
        }
        float4 o; o.x = a0; o.y = a1; o.z = a2; o.w = a3;
        *(float4*)&x_recon[(size_t)nn * 128 + c0] = o;
    }
}

// ---------------- launch ----------------

extern "C" void kernel_launch(void* const* d_in, const int* in_sizes, int n_in,
                              void* d_out, int out_size, void* d_ws, size_t ws_size,
                              hipStream_t stream) {
    const float* x    = (const float*)d_in[0];
    const int*   eidx = (const int*)d_in[1];
    const float* W1   = (const float*)d_in[2];
    const float* b1   = (const float*)d_in[3];
    const float* W2   = (const float*)d_in[4];
    const float* b2   = (const float*)d_in[5];
    const float* Wd   = (const float*)d_in[6];
    const float* bd   = (const float*)d_in[7];

    const int N = in_sizes[0] / 128;   // 100000
    const int E = in_sizes[1] / 2;     // 1600000
    const int* src = eidx;
    const int* dst = eidx + E;

    size_t off = 0;
    auto alloc = [&](size_t bytes) {
        void* p = (char*)d_ws + off;
        off += (bytes + 255) & ~(size_t)255;
        return p;
    };
    int*      cnt     = (int*)alloc((size_t)N * 4);
    float*    dinv    = (float*)alloc((size_t)N * 4);
    unsigned* bucket  = (unsigned*)alloc((size_t)N * CAP * 4);  // 25.6 MB, rank-major [CAP][N]
    unsigned* h1b     = (unsigned*)alloc((size_t)N * 64 * 4);   // bf16 [N,128]
    unsigned* h2b     = (unsigned*)alloc((size_t)N * 32 * 4);   // bf16 [N,64]
    unsigned* hrelu_b = (unsigned*)alloc((size_t)N * 64 * 4);   // bf16 [N,128]
    (void)ws_size;

    float* x_recon = (float*)d_out;                    // [N,128]
    float* z_out   = (float*)d_out + (size_t)N * 128;  // [N,64]

    const int gb = (N + 127) / 128;   // 782 gemm blocks
    // fill span: ceil(E/FILLW) rounded up to 4*TPB
    int span = (E + FILLW - 1) / FILLW;
    span = (span + TPB * 4 - 1) & ~(TPB * 4 - 1);
    const unsigned M = (unsigned)((8ULL << 32) / (unsigned)N);  // bin multiplier

    (void)hipMemsetAsync(cnt, 0, (size_t)N * 4, stream);

    // fused: filter-fill (XCD-affine) || gemm1
    fused1_k<<<8 * FILLW + gb, TPB, 0, stream>>>(x, W1, h1b, src, dst, cnt, bucket,
                                                 N, E, span, M);
    // dinv table
    dinv_k<<<(N + TPB - 1) / TPB, TPB, 0, stream>>>(cnt, dinv, N);

    // layer 1 aggregation (R8-exact)
    agg_k<64, true, true><<<(N + 3) / 4, TPB, 0, stream>>>(h1b, dinv, cnt, bucket, b1, hrelu_b, N);
    // layer 2 gemm
    gemm_k<128, 64, 4, false, true, true><<<gb, TPB, 0, stream>>>(hrelu_b, W2, nullptr, h2b, N);
    // layer 2 aggregation + fused decode
    agg2g_k<<<(N + 7) / 8, TPB, 0, stream>>>(h2b, dinv, cnt, bucket, b2, Wd, bd,
                                             z_out, x_recon, N);
}